// Round 15
// baseline (685.934 us; speedup 1.0000x reference)
//
#include <hip/hip_runtime.h>
#include <hip/hip_bf16.h>

typedef __bf16 bf16;
typedef __bf16 bf16x4 __attribute__((ext_vector_type(4)));
typedef __bf16 bf16x8 __attribute__((ext_vector_type(8)));
typedef float floatx4 __attribute__((ext_vector_type(4)));

#define MFMA16(a, b, c) __builtin_amdgcn_mfma_f32_16x16x32_bf16((a), (b), (c), 0, 0, 0)
#define SCALE_F 0.125f

// async global->LDS, 16B per lane; LDS dest = wave-uniform base + lane*16
#define GLDS(gp, lp) __builtin_amdgcn_global_load_lds( \
    (const __attribute__((address_space(1))) void*)(gp), \
    (__attribute__((address_space(3))) void*)(lp), 16, 0, 0)

// ---------------------------------------------------------------------------
// prep: all weight transposes + bias concat in ONE dispatch.
// ---------------------------------------------------------------------------
__global__ __launch_bounds__(256) void prep_kernel(const float* __restrict__ Wq, const float* __restrict__ Wk,
                                                   const float* __restrict__ Wv, const float* __restrict__ Wo,
                                                   const float* __restrict__ Wc,
                                                   const float* __restrict__ bq, const float* __restrict__ bk,
                                                   const float* __restrict__ bv,
                                                   bf16* __restrict__ wqkvT, bf16* __restrict__ woT,
                                                   bf16* __restrict__ wcT, float* __restrict__ bqkv) {
    const int z = blockIdx.z;
    const int tx = threadIdx.x, ty = threadIdx.y;   // block (32,8)
    if (z == 10) {
        int bid = blockIdx.y * 32 + blockIdx.x;
        if (bid < 12) {
            int i = bid * 256 + ty * 32 + tx;
            float v = (i < 1024) ? bq[i] : (i < 2048 ? bk[i - 1024] : bv[i - 2048]);
            bqkv[i] = v;
        }
        return;
    }
    __shared__ float tile[32][33];
    const float* in;
    bf16* out;
    int R;
    if (z < 3)      { in = (z == 0 ? Wq : (z == 1 ? Wk : Wv)); out = wqkvT + (size_t)z * 1048576; R = 1024; }
    else if (z < 6) { in = Wo + (size_t)(z - 3) * 1048576; out = woT + (size_t)(z - 3) * 1048576; R = 1024; }
    else            { in = Wc + (size_t)(z - 6) * 1048576; out = wcT + (z - 6) * 1024; R = 4096; }
    int bx = blockIdx.x * 32, by = blockIdx.y * 32;
#pragma unroll
    for (int i = 0; i < 32; i += 8)
        tile[ty + i][tx] = in[(size_t)(by + ty + i) * 1024 + bx + tx];
    __syncthreads();
#pragma unroll
    for (int i = 0; i < 32; i += 8)
        out[(size_t)(bx + ty + i) * R + by + tx] = (bf16)tile[tx][ty + i];
}

// ---------------------------------------------------------------------------
// Gates + selection scores + fused fp32->bf16 conversion of x.
// ---------------------------------------------------------------------------
__global__ __launch_bounds__(256) void gates_scores_kernel(const float* __restrict__ x,
                                                           const float* __restrict__ Wg, const float* __restrict__ bg,
                                                           const float* __restrict__ Ws, const float* __restrict__ bs,
                                                           float* __restrict__ gates, float* __restrict__ scores,
                                                           bf16* __restrict__ xb) {
    int row = blockIdx.x * 4 + (threadIdx.x >> 6);
    int lane = threadIdx.x & 63;
    const float* xr = x + (size_t)row * 1024 + lane * 16;
    float g0 = 0.f, g1 = 0.f, g2 = 0.f;
    double sc = 0.0;
    bf16x8 xo0, xo1;
#pragma unroll
    for (int i = 0; i < 16; i++) {
        float xv = xr[i];
        if (i < 8) xo0[i] = (bf16)xv; else xo1[i - 8] = (bf16)xv;
        int k = lane * 16 + i;
        g0 += xv * Wg[k * 3 + 0];
        g1 += xv * Wg[k * 3 + 1];
        g2 += xv * Wg[k * 3 + 2];
        sc += (double)(xv * Ws[k]);
    }
    bf16* xbp = xb + (size_t)row * 1024 + lane * 16;
    *(bf16x8*)xbp = xo0;
    *(bf16x8*)(xbp + 8) = xo1;
    for (int off = 1; off < 64; off <<= 1) {
        g0 += __shfl_xor(g0, off);
        g1 += __shfl_xor(g1, off);
        g2 += __shfl_xor(g2, off);
        sc += __shfl_xor(sc, off);
    }
    if (lane == 0) {
        g0 = 1.0f / (1.0f + __expf(-(g0 + bg[0])));
        g1 = 1.0f / (1.0f + __expf(-(g1 + bg[1])));
        g2 = 1.0f / (1.0f + __expf(-(g2 + bg[2])));
        float den = g0 + g1 + g2 + 1e-6f;
        gates[(size_t)row * 3 + 0] = g0 / den;
        gates[(size_t)row * 3 + 1] = g1 / den;
        gates[(size_t)row * 3 + 2] = g2 / den;
        scores[row] = (float)(sc + (double)bs[0]);
    }
}

// ---------------------------------------------------------------------------
// Top-k stage 1: PARTIAL rank counts. grid (16, 4, 4).
// ---------------------------------------------------------------------------
__global__ __launch_bounds__(256) void rank_kernel(const float* __restrict__ scores, int* __restrict__ rankP) {
    __shared__ float s[1024];
    const int b = blockIdx.z, jc = blockIdx.y;
    const int i = blockIdx.x * 256 + threadIdx.x;   // global query index
    const float* sb = scores + b * 4096;
    ((float4*)s)[threadIdx.x] = ((const float4*)(sb + jc * 1024))[threadIdx.x];
    __syncthreads();
    const float si = sb[i];
    const int jbase = jc * 1024;
    int cnt = 0;
#pragma unroll 4
    for (int jj = 0; jj < 1024; jj += 4) {
        float4 v = *(const float4*)(s + jj);
        int j0 = jbase + jj;
        cnt += (v.x > si) || (v.x == si && (j0 + 0) < i);
        cnt += (v.y > si) || (v.y == si && (j0 + 1) < i);
        cnt += (v.z > si) || (v.z == si && (j0 + 2) < i);
        cnt += (v.w > si) || (v.w == si && (j0 + 3) < i);
    }
    rankP[jc * 16384 + b * 4096 + i] = cnt;
}

// ---------------------------------------------------------------------------
// Top-k stage 2: sum partials; compact rank<512 in ascending-index order.
// ---------------------------------------------------------------------------
__global__ __launch_bounds__(1024) void select_kernel(const int* __restrict__ rankP, int* __restrict__ sidx) {
    __shared__ int psum[1024];
    int b = blockIdx.x, t = threadIdx.x;
    const int* rb = rankP + b * 4096;
    int f[4];
#pragma unroll
    for (int k = 0; k < 4; k++) {
        int idx = 4 * t + k;
        int r = rb[idx] + rb[16384 + idx] + rb[32768 + idx] + rb[49152 + idx];
        f[k] = r < 512;
    }
    psum[t] = f[0] + f[1] + f[2] + f[3];
    __syncthreads();
    for (int off = 1; off < 1024; off <<= 1) {
        int u = (t >= off) ? psum[t - off] : 0;
        __syncthreads();
        psum[t] += u;
        __syncthreads();
    }
    int pos = t ? psum[t - 1] : 0;
    int* ob = sidx + b * 512;
    if (f[0]) ob[pos++] = 4 * t + 0;
    if (f[1]) ob[pos++] = 4 * t + 1;
    if (f[2]) ob[pos++] = 4 * t + 2;
    if (f[3]) ob[pos++] = 4 * t + 3;
}

// ---------------------------------------------------------------------------
// add four fp32 partials + bias, convert to bf16 (comp K-split merge)
// ---------------------------------------------------------------------------
__global__ __launch_bounds__(256) void addcvt4_kernel(const float* __restrict__ P0, const float* __restrict__ P1,
                                                      const float* __restrict__ P2, const float* __restrict__ P3,
                                                      const float* __restrict__ bc, bf16* __restrict__ outp) {
    int i = blockIdx.x * 256 + threadIdx.x;    // 1,048,576 threads x 4 elems
    float4 a = ((const float4*)P0)[i];
    float4 b = ((const float4*)P1)[i];
    float4 c = ((const float4*)P2)[i];
    float4 d = ((const float4*)P3)[i];
    int col = (i << 2) & 1023;
    bf16x4 o;
    o[0] = (bf16)(a.x + b.x + c.x + d.x + bc[col + 0]);
    o[1] = (bf16)(a.y + b.y + c.y + d.y + bc[col + 1]);
    o[2] = (bf16)(a.z + b.z + c.z + d.z + bc[col + 2]);
    o[3] = (bf16)(a.w + b.w + c.w + d.w + bc[col + 3]);
    *(bf16x4*)(outp + ((size_t)i << 2)) = o;
}

// ---------------------------------------------------------------------------
// gemm3 body as device function (BT only): C(M,N) = A(M,K) @ Bt(N,K)^T + bias.
// m97 pattern: 128x128 tile, 16x16x32 bf16 MFMA, 4 waves, 4x4 frags.
// ---------------------------------------------------------------------------
template <bool F32OUT, bool ACC, bool REMAP>
__device__ __forceinline__ void gemm3_body(int nt, int mt, int zh, int zl, bf16* sA, bf16* sB,
                                           const bf16* __restrict__ A, const bf16* __restrict__ Bt,
                                           void* __restrict__ Cv, const float* __restrict__ bias, int biasz,
                                           int K, int lda, int ldb, int ldc,
                                           size_t sAhi, size_t sAlo, size_t sBhi, size_t sBlo,
                                           size_t sChi, size_t sClo, int mpbA, int mpbC) {
    const int t = threadIdx.x;
    const int lane = t & 63, quad = lane >> 4, l16 = lane & 15;
    const int wv = t >> 6, wm = wv >> 1, wn = wv & 1;
    A  += (size_t)zh * sAhi + (size_t)zl * sAlo;
    Bt += (size_t)zh * sBhi + (size_t)zl * sBlo;
    const size_t cofs = (size_t)zh * sChi + (size_t)zl * sClo;

    floatx4 acc[4][4] = {};

    const bf16* Ap = A + (size_t)(mt * 128 + (t >> 2)) * lda + (t & 3) * 8;
    const bf16* Bp = Bt + (size_t)(nt * 128 + (t >> 2)) * ldb + (t & 3) * 8;
    const size_t rA = (size_t)64 * lda, rB = (size_t)64 * ldb;
    bf16* lA0 = sA + wv * 512;          // wave-uniform LDS bases
    bf16* lA1 = sA + 2048 + wv * 512;
    bf16* lB0 = sB + wv * 512;
    bf16* lB1 = sB + 2048 + wv * 512;

    for (int k0 = 0; k0 < K; k0 += 32) {
        __syncthreads();
        GLDS(Ap + k0,      lA0);
        GLDS(Ap + rA + k0, lA1);
        GLDS(Bp + k0,      lB0);
        GLDS(Bp + rB + k0, lB1);
        __syncthreads();
        bf16x8 af[4], bfr[4];
#pragma unroll
        for (int i = 0; i < 4; i++) af[i] = *(const bf16x8*)(sA + (wm * 64 + i * 16 + l16) * 32 + quad * 8);
#pragma unroll
        for (int j = 0; j < 4; j++) bfr[j] = *(const bf16x8*)(sB + (wn * 64 + j * 16 + l16) * 32 + quad * 8);
#pragma unroll
        for (int i = 0; i < 4; i++)
#pragma unroll
            for (int j = 0; j < 4; j++) acc[i][j] = MFMA16(af[i], bfr[j], acc[i][j]);
    }

#pragma unroll
    for (int i = 0; i < 4; i++) {
        int gr0 = mt * 128 + wm * 64 + i * 16 + quad * 4;
#pragma unroll
        for (int j = 0; j < 4; j++) {
            int gc = nt * 128 + wn * 64 + j * 16 + l16;
            float bvl = bias ? bias[zl * biasz + gc] : 0.0f;
#pragma unroll
            for (int r = 0; r < 4; r++) {
                int row = gr0 + r;
                size_t crow = REMAP ? ((size_t)(row / mpbA) * mpbC + (row % mpbA)) : (size_t)row;
                size_t off = cofs + crow * ldc + gc;
                float v = acc[i][j][r] + bvl;
                if constexpr (F32OUT) {
                    float* Cf = (float*)Cv;
                    if constexpr (ACC) v += Cf[off];
                    Cf[off] = v;
                } else {
                    bf16* Cb = (bf16*)Cv;
                    if constexpr (ACC) v += (float)Cb[off];
                    Cb[off] = (bf16)v;
                }
            }
        }
    }
}

// ---------------------------------------------------------------------------
// original gemm3 kernel wrapper
// ---------------------------------------------------------------------------
template <bool NZF, bool F32OUT, bool ACC, bool REMAP>
__global__ __launch_bounds__(256) void gemm3(const bf16* __restrict__ A, const bf16* __restrict__ Bt,
                                             void* __restrict__ Cv, const float* __restrict__ bias, int biasz,
                                             int K, int lda, int ldb, int ldc, int zdiv,
                                             size_t sAhi, size_t sAlo, size_t sBhi, size_t sBlo,
                                             size_t sChi, size_t sClo, int mpbA, int mpbC) {
    __shared__ float4 smA[512], smB[512];  // 128x32 bf16 each
    const int mt = blockIdx.y;
    int nt, zh, zl;
    if constexpr (NZF) {
        zh = blockIdx.z;
        zl = blockIdx.x / zdiv;
        nt = blockIdx.x - zl * zdiv;
    } else {
        nt = blockIdx.x;
        int z = blockIdx.z;
        zh = z / zdiv;
        zl = z - zh * zdiv;
    }
    gemm3_body<F32OUT, ACC, REMAP>(nt, mt, zh, zl, (bf16*)smA, (bf16*)smB,
                                   A, Bt, Cv, bias, biasz, K, lda, ldb, ldc,
                                   sAhi, sAlo, sBhi, sBlo, sChi, sClo, mpbA, mpbC);
}

// ---------------------------------------------------------------------------
// gemm3_pair: TWO independent gemm3 problems in one dispatch.
// Grid: (max nx, max ny, nzA+nzB); side B bounds-checked.
// ---------------------------------------------------------------------------
template <bool F32OUT>
__global__ __launch_bounds__(256) void gemm3_pair(int nzA, int nxB, int nyB,
        const bf16* __restrict__ A1, const bf16* __restrict__ B1, void* __restrict__ C1,
        int K1, int lda1, int ldb1, int ldc1, size_t sAhi1, size_t sBhi1, size_t sChi1,
        const bf16* __restrict__ A2, const bf16* __restrict__ B2, void* __restrict__ C2,
        int K2, int lda2, int ldb2, int ldc2, size_t sAhi2, size_t sBhi2, size_t sChi2) {
    __shared__ float4 smA[512], smB[512];
    if ((int)blockIdx.z < nzA) {
        gemm3_body<F32OUT, false, false>(blockIdx.x, blockIdx.y, blockIdx.z, 0, (bf16*)smA, (bf16*)smB,
                                         A1, B1, C1, nullptr, 0, K1, lda1, ldb1, ldc1,
                                         sAhi1, 0, sBhi1, 0, sChi1, 0, 1, 1);
    } else {
        if ((int)blockIdx.x >= nxB || (int)blockIdx.y >= nyB) return;
        gemm3_body<F32OUT, false, false>(blockIdx.x, blockIdx.y, blockIdx.z - nzA, 0, (bf16*)smA, (bf16*)smB,
                                         A2, B2, C2, nullptr, 0, K2, lda2, ldb2, ldc2,
                                         sAhi2, 0, sBhi2, 0, sChi2, 0, 1, 1);
    }
}

// ---------------------------------------------------------------------------
// win QK^T (256 gemm3 blocks, old grid (2,2,64) flattened) + gather (1024
// copy blocks) merged into one dispatch: independent work, disjoint buffers
// (Swin @136 vs sq/sk/sv @172+), both depend only on QKV.
// ---------------------------------------------------------------------------
__global__ __launch_bounds__(256) void winqkt_gather_kernel(
        const bf16* __restrict__ qf, const bf16* __restrict__ kf, float* __restrict__ Swin,
        const bf16* __restrict__ Vf, const int* __restrict__ sidx,
        bf16* __restrict__ sq, bf16* __restrict__ sk, bf16* __restrict__ sv) {
    if ((int)blockIdx.x < 256) {
        __shared__ float4 smA[512], smB[512];
        int b = blockIdx.x;
        int nt = b & 1, mt = (b >> 1) & 1, zz = b >> 2;
        int zh = zz >> 4, zl = zz & 15;
        gemm3_body<true, false, false>(nt, mt, zh, zl, (bf16*)smA, (bf16*)smB,
                                       qf, kf, Swin, nullptr, 0, 1024, 1024, 1024, 256,
                                       (size_t)4194304, (size_t)131072, (size_t)4194304, (size_t)131072,
                                       (size_t)1048576, (size_t)65536, 1, 1);
        return;
    }
    int e = (blockIdx.x - 256) * 256 + threadIdx.x;
    int col = (e & 127) * 8;
    int i = (e >> 7) & 511;
    int b = e >> 16;
    int src = b * 4096 + (sidx[b * 512 + i] & 4095);
    size_t so = (size_t)src * 1024 + col;
    size_t dofs = (size_t)(b * 512 + i) * 1024 + col;
    *(float4*)(sq + dofs) = *(const float4*)(qf + so);
    *(float4*)(sk + dofs) = *(const float4*)(kf + so);
    *(float4*)(sv + dofs) = *(const float4*)(Vf + so);
}

// ---------------------------------------------------------------------------
// 256x256 8-phase GEMM (T2+T3+T4+T5). R3-measured main loop (105-112 us QKV,
// MfmaUtil ~41, 0 bank conflicts). K_STEP=64, 128 KiB LDS, 8 waves (2M x 4N).
// R8 LDS-staged vectorized epilogue. Grid product divisible by 8; K%128==0.
// ---------------------------------------------------------------------------
#define BARx()   asm volatile("s_barrier" ::: "memory")
#define LGKM0()  asm volatile("s_waitcnt lgkmcnt(0)" ::: "memory")
#define VMC6()   asm volatile("s_waitcnt vmcnt(6)" ::: "memory")

#define LD_A(bsel, qm) { \
    const bf16* _p = lds + (bsel) * 32768 + (((qm) << 7) + (wm << 6) + l16) * 64; \
    _Pragma("unroll") \
    for (int m = 0; m < 4; m++) { \
        a[m][0] = *(const bf16x8*)(_p + (m << 10) + cg0); \
        a[m][1] = *(const bf16x8*)(_p + (m << 10) + cg1); \
    } }

#define LD_B(bsel, qn) { \
    const bf16* _p = lds + (bsel) * 32768 + 16384 + (((qn) << 7) + (wn << 5) + l16) * 64; \
    _Pragma("unroll") \
    for (int n = 0; n < 2; n++) { \
        b[qn][n][0] = *(const bf16x8*)(_p + (n << 10) + cg0); \
        b[qn][n][1] = *(const bf16x8*)(_p + (n << 10) + cg1); \
    } }

#define ST_A(bsel, h, ko) { \
    bf16* _d = lds + (bsel) * 32768 + (((h) << 7) + (wv << 3)) * 64; \
    const bf16* _g = Ab + (size_t)((h) << 7) * lda + (ko); \
    GLDS(_g, _d); \
    GLDS(_g + ((size_t)lda << 6), _d + 4096); }

#define ST_B(bsel, h, ko) { \
    bf16* _d = lds + (bsel) * 32768 + 16384 + (((h) << 7) + (wv << 3)) * 64; \
    const bf16* _g = Bb + (size_t)((h) << 7) * ldb + (ko); \
    GLDS(_g, _d); \
    GLDS(_g + ((size_t)ldb << 6), _d + 4096); }

#define PH_MMA(qm, qn) { \
    __builtin_amdgcn_s_setprio(1); \
    _Pragma("unroll") \
    for (int kk = 0; kk < 2; kk++) \
    _Pragma("unroll") \
    for (int m = 0; m < 4; m++) \
    _Pragma("unroll") \
    for (int n = 0; n < 2; n++) \
        acc[qm][qn][m][n] = MFMA16(a[m][kk], b[qn][n][kk], acc[qm][qn][m][n]); \
    __builtin_amdgcn_s_setprio(0); }

template <bool F32OUT, bool ACC, bool REMAP>
__device__ __forceinline__ void gemm256_body(int mt, int nt, int zh, int zl, float4* ldsv,
        const bf16* __restrict__ A, const bf16* __restrict__ Bt,
        void* __restrict__ Cv, const float* __restrict__ bias, int biasz,
        int K, int lda, int ldb, int ldc,
        size_t sAhi, size_t sAlo, size_t sBhi, size_t sBlo,
        size_t sChi, size_t sClo, int mpbA, int mpbC) {
    bf16* lds = (bf16*)ldsv;
    const int t = threadIdx.x;
    const int lane = t & 63, quad = lane >> 4, l16 = lane & 15;
    const int wv = t >> 6, wm = wv >> 2, wn = wv & 3;

    A  += (size_t)zh * sAhi + (size_t)zl * sAlo;
    Bt += (size_t)zh * sBhi + (size_t)zl * sBlo;
    const size_t cofs = (size_t)zh * sChi + (size_t)zl * sClo;

    // staging: wave wv stages rows wv*8+(lane>>3) of each 64-row call block;
    // global source column pre-swizzled so LDS stays linear (m104 constraint)
    const int srow = (wv << 3) + (lane >> 3);
    const int scol = (((lane & 7) ^ ((lane >> 3) & 7)) << 3);
    const bf16* Ab = A + (size_t)(mt * 256 + srow) * lda + scol;
    const bf16* Bb = Bt + (size_t)(nt * 256 + srow) * ldb + scol;
    const int swz = l16 & 7;
    const int cg0 = ((quad ^ swz) << 3);         // kk=0 16B-granule (elements)
    const int cg1 = (((4 | quad) ^ swz) << 3);   // kk=1

    floatx4 acc[2][2][4][2] = {};
    bf16x8 a[4][2], b[2][2][2];     // A single-buffered, B kept per-qn

    const int NT = K >> 6;          // 64-wide K-tiles; K % 128 == 0 required
    // prologue: both tiles fully staged
    ST_A(0, 0, 0);  ST_B(0, 0, 0);  ST_B(0, 1, 0);  ST_A(0, 1, 0);
    ST_A(1, 0, 64); ST_B(1, 0, 64); ST_B(1, 1, 64); ST_A(1, 1, 64);
    VMC6();                          // 16 issued -> tile0's 8 + b1.Ah0 landed
    BARx();

#pragma unroll 1
    for (int it = 0; it < (NT >> 1); ++it) {
        const int kt = it << 1;
        const int ko2 = ((kt + 2 < NT) ? kt + 2 : NT - 1) << 6;     // clamped: staged-but-unread past end
        const int ko3 = ((kt + 3 < NT) ? kt + 3 : NT - 1) << 6;
        // p0: q(0,0) buf0 — no ST
        LD_B(0, 0); LD_A(0, 0);
        PH_MMA(0, 0);
        LGKM0(); BARx();
        // p1: q(0,1)
        LD_B(0, 1);
        ST_A(0, 0, ko2);
        PH_MMA(0, 1);
        LGKM0(); BARx();
        // p2: q(1,1)
        LD_A(0, 1);
        ST_B(0, 0, ko2);
        PH_MMA(1, 1);
        LGKM0(); BARx();
        // p3: q(1,0) — no reads; vmcnt checkpoint
        ST_B(0, 1, ko2);
        PH_MMA(1, 0);
        VMC6(); BARx();
        // p4: q(0,0) buf1
        LD_B(1, 0); LD_A(1, 0);
        ST_A(0, 1, ko2);
        PH_MMA(0, 0);
        LGKM0(); BARx();
        // p5: q(0,1)
        LD_B(1, 1);
        ST_A(1, 0, ko3);
        PH_MMA(0, 1);
        LGKM0(); BARx();
        // p6: q(1,1)
        LD_A(1, 1);
        ST_B(1, 0, ko3);
        PH_MMA(1, 1);
        LGKM0(); BARx();
        // p7: q(1,0) — two STs; vmcnt checkpoint
        ST_B(1, 1, ko3);
        ST_A(1, 1, ko3);
        PH_MMA(1, 0);
        VMC6(); BARx();
    }

    // ---- epilogue ----
    asm volatile("s_waitcnt vmcnt(0)" ::: "memory");
    BARx();

    if constexpr (!ACC && !REMAP) {
        const int STE = F32OUT ? 260 : 264;
        float* ldsf = (float*)ldsv;
        bf16* ldsh = (bf16*)ldsv;
#pragma unroll
        for (int qm = 0; qm < 2; qm++)
#pragma unroll
        for (int mh = 0; mh < 2; mh++) {
#pragma unroll
            for (int qn = 0; qn < 2; qn++)
#pragma unroll
            for (int n = 0; n < 2; n++) {
                const int ccol = qn * 128 + wn * 32 + n * 16 + l16;
                const float bvl = bias ? bias[zl * biasz + nt * 256 + ccol] : 0.0f;
#pragma unroll
                for (int mp = 0; mp < 2; mp++) {
                    const int lr0 = wm * 32 + mp * 16 + quad * 4;
#pragma unroll
                    for (int r = 0; r < 4; r++) {
                        float v = acc[qm][qn][mh * 2 + mp][n][r] + bvl;
                        if constexpr (F32OUT) ldsf[(lr0 + r) * STE + ccol] = v;
                        else                  ldsh[(lr0 + r) * STE + ccol] = (bf16)v;
                    }
                }
            }
            LGKM0(); BARx();
            if constexpr (F32OUT) {
                float* Cf = (float*)Cv;
#pragma unroll
                for (int i = 0; i < 8; i++) {
                    int idx = i * 512 + t;
                    int row = idx >> 6, c4 = (idx & 63) << 2;
                    float4 vv = *(float4*)(ldsf + row * STE + c4);
                    int grow = mt * 256 + qm * 128 + ((row >> 5) << 6) + mh * 32 + (row & 31);
                    *(float4*)(Cf + cofs + (size_t)grow * ldc + nt * 256 + c4) = vv;
                }
            } else {
                bf16* Cb = (bf16*)Cv;
#pragma unroll
                for (int i = 0; i < 4; i++) {
                    int idx = i * 512 + t;
                    int row = idx >> 5, c8 = (idx & 31) << 3;
                    float4 vv = *(float4*)(ldsh + row * STE + c8);
                    int grow = mt * 256 + qm * 128 + ((row >> 5) << 6) + mh * 32 + (row & 31);
                    *(float4*)(Cb + cofs + (size_t)grow * ldc + nt * 256 + c8) = vv;
                }
            }
            LGKM0(); BARx();
        }
    } else {
        // scalar fallback (unused by current call sites)
#pragma unroll
        for (int qm = 0; qm < 2; qm++)
#pragma unroll
        for (int m = 0; m < 4; m++) {
            int gr0 = mt * 256 + qm * 128 + wm * 64 + m * 16 + quad * 4;
#pragma unroll
            for (int qn = 0; qn < 2; qn++)
#pragma unroll
            for (int n = 0; n < 2; n++) {
                int gc = nt * 256 + qn * 128 + wn * 32 + n * 16 + l16;
                float bvl = bias ? bias[zl * biasz + gc] : 0.0f;
#pragma unroll
                for (int r = 0; r < 4; r++) {
                    int row = gr0 + r;
                    size_t crow = REMAP ? ((size_t)(row / mpbA) * mpbC + (row % mpbA)) : (size_t)row;
                    size_t off = cofs + crow * ldc + gc;
                    float v = acc[qm][qn][m][n][r] + bvl;
                    if constexpr (F32OUT) {
                        float* Cf = (float*)Cv;
                        if constexpr (ACC) v += Cf[off];
                        Cf[off] = v;
                    } else {
                        bf16* Cb = (bf16*)Cv;
                        if constexpr (ACC) v += (float)Cb[off];
                        Cb[off] = (bf16)v;
                    }
                }
            }
        }
    }
}

template <bool NZF, bool F32OUT, bool ACC, bool REMAP>
__global__ __launch_bounds__(512, 2) void gemm256(const bf16* __restrict__ A, const bf16* __restrict__ Bt,
                                                  void* __restrict__ Cv, const float* __restrict__ bias, int biasz,
                                                  int K, int lda, int ldb, int ldc, int zdiv,
                                                  size_t sAhi, size_t sAlo, size_t sBhi, size_t sBlo,
                                                  size_t sChi, size_t sClo, int mpbA, int mpbC) {
    __shared__ float4 ldsv[8192];   // 128 KiB: buf0 {A|B} , buf1 {A|B}
    // XCD-chunked bijective remap over (x,y); callers guarantee nwg % 8 == 0
    const int gx = gridDim.x;
    int lin = blockIdx.x + gx * blockIdx.y;
    const int chunk = (gx * gridDim.y) >> 3;
    lin = (lin & 7) * chunk + (lin >> 3);
    const int bx = lin % gx;
    const int mt = lin / gx;

    int nt, zh, zl;
    if constexpr (NZF) {
        zh = blockIdx.z;
        zl = bx / zdiv;
        nt = bx - zl * zdiv;
    } else {
        nt = bx;
        int z = blockIdx.z;
        zh = z / zdiv;
        zl = z - zh * zdiv;
    }
    gemm256_body<F32OUT, ACC, REMAP>(mt, nt, zh, zl, ldsv, A, Bt, Cv, bias, biasz,
                                     K, lda, ldb, ldc, sAhi, sAlo, sBhi, sBlo, sChi, sClo, mpbA, mpbC);
}

#undef LD_A
#undef LD_B
#undef ST_A
#undef ST_B
#undef PH_MMA

// ---------------------------------------------------------------------------
// shared softmax / transpose device helpers
// ---------------------------------------------------------------------------
__device__ __forceinline__ void sm_body(const float* __restrict__ srow, bf16* __restrict__ prow,
                                        int npt, float gate, float* red) {
    const int t = threadIdx.x;
    float v[4];
    float m = -1e30f;
    for (int i = 0; i < npt; i++) { v[i] = srow[t + (i << 8)] * SCALE_F; m = fmaxf(m, v[i]); }
    for (int off = 1; off < 64; off <<= 1) m = fmaxf(m, __shfl_xor(m, off));
    const int wvv = t >> 6, lane = t & 63;
    if (lane == 0) red[wvv] = m;
    __syncthreads();
    m = fmaxf(fmaxf(red[0], red[1]), fmaxf(red[2], red[3]));
    float e[4], s = 0.f;
    for (int i = 0; i < npt; i++) { e[i] = __expf(v[i] - m); s += e[i]; }
    for (int off = 1; off < 64; off <<= 1) s += __shfl_xor(s, off);
    if (lane == 0) red[4 + wvv] = s;
    __syncthreads();
    s = red[4] + red[5] + red[6] + red[7];
    const float fac = gate / s;
    for (int i = 0; i < npt; i++) prow[t + (i << 8)] = (bf16)(e[i] * fac);
}

__device__ __forceinline__ void tp_body(const bf16* __restrict__ tin, bf16* __restrict__ tout,
                                        int TR, int TC, int tb, bf16 (*tile)[33]) {
    const int t = threadIdx.x;
    int bx = (tb & 31) * 32, by = (tb >> 5) * 32;
    int tx = t & 31, ty = t >> 5;
#pragma unroll
    for (int i = 0; i < 32; i += 8)
        tile[ty + i][tx] = tin[(size_t)(by + ty + i) * TC + bx + tx];
    __syncthreads();
#pragma unroll
    for (int i = 0; i < 32; i += 8)
        tout[(size_t)(bx + ty + i) * TR + by + tx] = tile[tx][ty + i];
}

// ---------------------------------------------------------------------------
// Merged win softmax + vf transpose
// ---------------------------------------------------------------------------
__global__ __launch_bounds__(256) void smtb_win_kernel(const float* __restrict__ S, bf16* __restrict__ P,
                                                       const float* __restrict__ gates, int nsm,
                                                       const bf16* __restrict__ tin, bf16* __restrict__ tout) {
    __shared__ float red[8];
    __shared__ bf16 tile[32][33];
    if ((int)blockIdx.x >= nsm) {
        tp_body(tin, tout, 16384, 1024, blockIdx.x - nsm, tile);
        return;
    }
    const int row = blockIdx.x;
    int zz = row >> 8;
    int gpos = (zz / 16) * 4096 + (zz % 16) * 256 + (row & 255);
    sm_body(S + (size_t)row * 256, P + (size_t)row * 256, 1, gates[gpos * 3 + 2], red);
}

// ---------------------------------------------------------------------------
// Merged comp+sel softmax + cv/sv transposes (4 independent block ranges)
// ---------------------------------------------------------------------------
__global__ __launch_bounds__(256) void smtb2_kernel(const float* __restrict__ S0, bf16* __restrict__ P0,
                                                    const float* __restrict__ S1, bf16* __restrict__ P1,
                                                    const float* __restrict__ gates,
                                                    const bf16* __restrict__ cv, bf16* __restrict__ cvT,
                                                    const bf16* __restrict__ sv, bf16* __restrict__ svT) {
    __shared__ float red[8];
    __shared__ bf16 tile[32][33];
    const int i = blockIdx.x;
    if (i < 4096) {
        int gpos = (i >> 10) * 4096 + (i & 1023);
        sm_body(S0 + (size_t)i * 1024, P0 + (size_t)i * 1024, 4, gates[gpos * 3 + 0], red);
    } else if (i < 8192) {
        tp_body(cv, cvT, 4096, 1024, i - 4096, tile);
    } else if (i < 10240) {
        int row = i - 8192;
        int gpos = (row >> 9) * 4096 + (row & 511);
        sm_body(S1 + (size_t)row * 512, P1 + (size_t)row * 512, 2, gates[gpos * 3 + 1], red);
    } else {
        tp_body(sv, svT, 2048, 1024, i - 10240, tile);
    }
}

// ---------------------------------------------------------------------------
// Residual (0.5/0.5) + partial sums + LayerNorm, in-place on fp32 out.
// out_row += compPr (idx<1024) += selPr (idx<512): same fp32 add order as
// the old serial ACC chain -> bitwise identical.
// ---------------------------------------------------------------------------
__global__ __launch_bounds__(256) void ln_kernel(float* __restrict__ acc, const float* __restrict__ x,
                                                 const float* __restrict__ compPr, const float* __restrict__ selPr) {
    __shared__ float red[8];
    int row = blockIdx.x, t = threadIdx.x;
    int b = row >> 12, idx = row & 4095;
    float4 a = ((const float4*)(acc + (size_t)row * 1024))[t];
    if (idx < 1024) {
        float4 c = ((const float4*)(compPr + (size_t)(b * 1024 + idx) * 1024))[t];
        a.x += c.x; a.y += c.y; a.z += c.z; a.w += c.w;
    }
    if (idx < 512) {
        float4 s4 = ((const float4*)(selPr + (size_t)(b * 512 + idx) * 1024))[t];
        a.x += s4.x; a.y += s4.y; a.z += s4.z; a.w += s4.w;
    }
    float4 xv = ((const float4*)(x + (size_t)row * 1024))[t];
    float y[4];
    y[0] = 0.5f * a.x + 0.5f * xv.x;
    y[1] = 0.5f * a.y + 0.5f * xv.y;
    y[2] = 0.5f * a.z + 0.5f * xv.z;
    y[3] = 0.5f * a.w + 0.5f * xv.w;
    float s = 0.f, s2 = 0.f;
#pragma unroll
    for (int i = 0; i < 4; i++) { s += y[i]; s2 += y[i] * y[i]; }
    for (int off = 1; off < 64; off <<= 1) { s += __shfl_xor(s, off); s2 += __shfl_xor(s2, off); }
    int wvv = t >> 6, lane = t & 63;
    if (lane == 0) { red[wvv] = s; red[4 + wvv] = s2; }
    __syncthreads();
    s = red[0] + red[1] + red[2] + red[3];
    s2 = red[4] + red[5] + red[6] + red[7];
    float mu = s * (1.0f / 1024.0f);
    float var = s2 * (1.0f / 1024.0f) - mu * mu;
    float rs = rsqrtf(var + 1e-6f);
    float4 o;
    o.x = (y[0] - mu) * rs;
    o.y = (y[1] - mu) * rs;
    o.z = (y[2] - mu) * rs;
    o.w = (y[3] - mu) * rs;
    ((float4*)(acc + (size_t)row * 1024))[t] = o;
}

// ---------------------------------------------------------------------------
extern "C" void kernel_launch(void* const* d_in, const int* in_sizes, int n_in,
                              void* d_out, int out_size, void* d_ws, size_t ws_size,
                              hipStream_t stream) {
    (void)in_sizes; (void)n_in; (void)out_size; (void)ws_size;
    const float* x  = (const float*)d_in[0];
    const float* Wq = (const float*)d_in[1];
    const float* bq = (const float*)d_in[2];
    const float* Wk = (const float*)d_in[3];
    const float* bk = (const float*)d_in[4];
    const float* Wv = (const float*)d_in[5];
    const float* bv = (const float*)d_in[6];
    const float* Wo = (const float*)d_in[7];
    const float* bo = (const float*)d_in[8];
    const float* Wg = (const float*)d_in[9];
    const float* bg = (const float*)d_in[10];
    const float* Wc = (const float*)d_in[11];
    const float* bc = (const float*)d_in[12];
    const float* Ws = (const float*)d_in[13];
    const float* bs = (const float*)d_in[14];
    float* out = (float*)d_out;

    // ---- workspace (~189 MB peak; phase-ordered region reuse) ----
    char* w = (char*)d_ws;
    const size_t MB = 1024 * 1024;
    // region A (0..32): xb [gates->compGEMM] -> Pwin [win] -> cq/ck/cv/Pcomp [comp branch]
    bf16* xb    = (bf16*)(w + 0 * MB);    // 32
    bf16* Pwin  = (bf16*)(w + 0 * MB);    // 8
    bf16* cq    = (bf16*)(w + 0 * MB);    // 8
    bf16* ck    = (bf16*)(w + 8 * MB);    // 8
    bf16* cv    = (bf16*)(w + 16 * MB);   // 8
    bf16* Pcomp = (bf16*)(w + 24 * MB);   // 8
    // sel small buffers (live after merged QK^T; cq/ck dead then)
    bf16* Psel  = (bf16*)(w + 4 * MB);    // 2
    bf16* sel_o = (bf16*)(w + 6 * MB);    // 4
    // mid regions
    bf16* qf    = (bf16*)(w + 32 * MB);   // 32 [QKV -> S_win]
    bf16* vfT   = (bf16*)(w + 32 * MB);   // 32 [after S_win]
    bf16* kf    = (bf16*)(w + 64 * MB);   // 32 [QKV -> S_win]
    bf16* win_o = (bf16*)(w + 64 * MB);   // 32 [after S_win]
    bf16* vf    = (bf16*)(w + 96 * MB);   // 32 [QKV -> vfT transpose/gather]
    bf16* comp  = (bf16*)(w + 128 * MB);  // 8  [compGEMM -> comp qkv]
    // comp K-split partials (4 x 16 MB fp32) overlay qf/kf (dead until QKV)
    float* compP = (float*)(w + 32 * MB); // 64 [32..96]
    // projection partials overlay vfT region (dead after win-PV):
    float* compPr = (float*)(w + 32 * MB); // 16 [32..48]
    float* selPr  = (float*)(w + 48 * MB); // 8  [48..56]
    // rank partials (256 KB) overlay vf (dead until QKV gemm writes it)
    int* rankP = (int*)(w + 96 * MB);
    // cvT in vf region (96..104): vf dead after win-branch transpose
    bf16* cvT = (bf16*)(w + 96 * MB);     // 8 [comp branch only]
    // Ssel at 104..108 (vf region, dead at comp-branch time)
    float* SselN = (float*)(w + 104 * MB); // 4
    // region B (136..152): Swin [win] -> Scomp [comp] -> comp_o
    float* Swin  = (float*)(w + 136 * MB);  // 16
    float* Scomp = (float*)(w + 136 * MB);  // 16
    bf16* comp_o = (bf16*)(w + 144 * MB);   // 8
    // weights (transposed bf16)
    bf16* wqkvT = (bf16*)(w + 152 * MB);  // 6 (wq|wk|wv, 1024-row segments)
    bf16* wcT   = (bf16*)(w + 158 * MB);  // 8
    bf16* woT0  = (bf16*)(w + 166 * MB);  // 2
    bf16* woT1  = (bf16*)(w + 168 * MB);  // 2
    bf16* woT2  = (bf16*)(w + 170 * MB);  // 2
    // sel gather buffers (parked high; live gather -> sel branch)
    bf16* sq    = (bf16*)(w + 172 * MB);  // 4
    bf16* sk    = (bf16*)(w + 176 * MB);  // 4
    bf16* sv    = (bf16*)(w + 180 * MB);  // 4
    bf16* svT   = (bf16*)(w + 184 * MB);  // 4
    // smalls
    float* bqkv    = (float*)(w + 188 * MB);
    float* gatesF  = bqkv + 3072;
    float* scoresF = gatesF + 49152;
    int*   sidx    = (int*)(scoresF + 16384);

    dim3 tb(32, 8);

    // ---- prep: gates+scores+x->bf16 (fused); all transposes + bconcat; topk ----
    gates_scores_kernel<<<4096, 256, 0, stream>>>(x, Wg, bg, Ws, bs, gatesF, scoresF, xb);
    prep_kernel<<<dim3(32, 32, 11), tb, 0, stream>>>(Wq, Wk, Wv, Wo, Wc, bq, bk, bv, wqkvT, woT0, wcT, bqkv);
    rank_kernel<<<dim3(16, 4, 4), 256, 0, stream>>>(scoresF, rankP);
    select_kernel<<<4, 1024, 0, stream>>>(rankP, sidx);

    // ---- compressed tokens FIRST (qf/kf free): 4-way K-split + merge ----
    gemm256<false,true,false,false><<<dim3(4, 16, 4), 512, 0, stream>>>(
        xb, wcT, compP, nullptr, 0, 1024, 4096, 4096, 1024, 1,
        (size_t)1024, 0, (size_t)1024, 0, (size_t)4194304, 0, 1, 1);
    addcvt4_kernel<<<4096, 256, 0, stream>>>(compP, compP + (size_t)4194304,
                                             compP + (size_t)8388608, compP + (size_t)12582912, bc, comp);

    // ---- fused Q/K/V: 256^2 8-phase, N-fused z ----
    gemm256<true,false,false,false><<<dim3(12, 64, 1), 512, 0, stream>>>(
        xb, wqkvT, qf, bqkv, 1024, 1024, 1024, 1024, 1024, 4,
        0, 0, 0, (size_t)1048576, 0, (size_t)16777216, 1, 1);

    // ---- merged: win QK^T (256 gemm3 blocks) + gather (1024 copy blocks) ----
    winqkt_gather_kernel<<<1280, 256, 0, stream>>>(qf, kf, Swin, vf, sidx, sq, sk, sv);

    // ---- win softmax + vf transpose ----
    smtb_win_kernel<<<32768, 256, 0, stream>>>(Swin, Pwin, gatesF, 16384, vf, vfT);
    gemm3<false,false,false,false><<<dim3(8, 2, 64), 256, 0, stream>>>(
        Pwin, vfT, win_o, nullptr, 0, 256, 256, 16384, 1024, 16,
        (size_t)1048576, (size_t)65536, (size_t)4096, (size_t)128, (size_t)4194304, (size_t)262144, 1, 1);
    // ---- win projection (gemm256, 256 blocks = 1 full round) -> out + bo ----
    gemm256<false,true,false,false><<<dim3(4, 64, 1), 512, 0, stream>>>(
        win_o, woT2, out, bo, 0, 1024, 1024, 1024, 1024, 1, 0, 0, 0, 0, 0, 0, 1, 1);

    // ---- COMP QKV (needed by merged QK^T pair) ----
    gemm256<true,false,false,false><<<dim3(12, 16, 1), 512, 0, stream>>>(
        comp, wqkvT, cq, bqkv, 1024, 1024, 1024, 1024, 1024, 4,
        0, 0, 0, (size_t)1048576, 0, (size_t)4194304, 1, 1);

    // ---- merged QK^T: Scomp (cq@ck) + Ssel (sq@sk) in one dispatch ----
    gemm3_pair<true><<<dim3(8, 8, 8), 256, 0, stream>>>(4, 4, 4,
        cq, ck, Scomp, 1024, 1024, 1024, 1024, (size_t)1048576, (size_t)1048576, (size_t)1048576,
        sq, sk, SselN, 1024, 1024, 1024, 512, (size_t)524288, (size_t)524288, (size_t)262144);

    // ---- merged softmaxes + V transposes (comp + sel) ----
    smtb2_kernel<<<12288, 256, 0, stream>>>(Scomp, Pcomp, SselN, Psel, gatesF, cv, cvT, sv, svT);

    // ---- merged PV: comp (Pcomp@cvT) + sel (Psel@svT) ----
    gemm3_pair<false><<<dim3(8, 8, 8), 256, 0, stream>>>(4, 8, 4,
        Pcomp, cvT, comp_o, 1024, 1024, 4096, 1024, (size_t)1048576, (size_t)1024, (size_t)1048576,
        Psel, svT, sel_o, 512, 512, 2048, 1024, (size_t)262144, (size_t)512, (size_t)524288);

    // ---- comp/sel projections -> fp32 partials (one gemm3_pair dispatch;
    //      summed in ln with the same fp32 add order as the old ACC chain) ----
    gemm3_pair<true><<<dim3(8, 32, 2), 256, 0, stream>>>(1, 8, 16,
        comp_o, woT0, compPr, 1024, 1024, 1024, 1024, 0, 0, 0,
        sel_o, woT1, selPr, 1024, 1024, 1024, 1024, 0, 0, 0);

    // ---- residual + partial sums + LN in place on fp32 d_out ----
    ln_kernel<<<16384, 256, 0, stream>>>(out, x, compPr, selPr);
}

// Round 17
// 676.640 us; speedup vs baseline: 1.0137x; 1.0137x over previous
//
#include <hip/hip_runtime.h>
#include <hip/hip_bf16.h>

typedef __bf16 bf16;
typedef __bf16 bf16x4 __attribute__((ext_vector_type(4)));
typedef __bf16 bf16x8 __attribute__((ext_vector_type(8)));
typedef float floatx4 __attribute__((ext_vector_type(4)));

#define MFMA16(a, b, c) __builtin_amdgcn_mfma_f32_16x16x32_bf16((a), (b), (c), 0, 0, 0)
#define SCALE_F 0.125f

// async global->LDS, 16B per lane; LDS dest = wave-uniform base + lane*16
#define GLDS(gp, lp) __builtin_amdgcn_global_load_lds( \
    (const __attribute__((address_space(1))) void*)(gp), \
    (__attribute__((address_space(3))) void*)(lp), 16, 0, 0)

// ---------------------------------------------------------------------------
// prep: all weight transposes + bias concat in ONE dispatch.
// ---------------------------------------------------------------------------
__global__ __launch_bounds__(256) void prep_kernel(const float* __restrict__ Wq, const float* __restrict__ Wk,
                                                   const float* __restrict__ Wv, const float* __restrict__ Wo,
                                                   const float* __restrict__ Wc,
                                                   const float* __restrict__ bq, const float* __restrict__ bk,
                                                   const float* __restrict__ bv,
                                                   bf16* __restrict__ wqkvT, bf16* __restrict__ woT,
                                                   bf16* __restrict__ wcT, float* __restrict__ bqkv) {
    const int z = blockIdx.z;
    const int tx = threadIdx.x, ty = threadIdx.y;   // block (32,8)
    if (z == 10) {
        int bid = blockIdx.y * 32 + blockIdx.x;
        if (bid < 12) {
            int i = bid * 256 + ty * 32 + tx;
            float v = (i < 1024) ? bq[i] : (i < 2048 ? bk[i - 1024] : bv[i - 2048]);
            bqkv[i] = v;
        }
        return;
    }
    __shared__ float tile[32][33];
    const float* in;
    bf16* out;
    int R;
    if (z < 3)      { in = (z == 0 ? Wq : (z == 1 ? Wk : Wv)); out = wqkvT + (size_t)z * 1048576; R = 1024; }
    else if (z < 6) { in = Wo + (size_t)(z - 3) * 1048576; out = woT + (size_t)(z - 3) * 1048576; R = 1024; }
    else            { in = Wc + (size_t)(z - 6) * 1048576; out = wcT + (z - 6) * 1024; R = 4096; }
    int bx = blockIdx.x * 32, by = blockIdx.y * 32;
#pragma unroll
    for (int i = 0; i < 32; i += 8)
        tile[ty + i][tx] = in[(size_t)(by + ty + i) * 1024 + bx + tx];
    __syncthreads();
#pragma unroll
    for (int i = 0; i < 32; i += 8)
        out[(size_t)(bx + ty + i) * R + by + tx] = (bf16)tile[tx][ty + i];
}

// ---------------------------------------------------------------------------
// Gates + selection scores + fused fp32->bf16 conversion of x.
// ---------------------------------------------------------------------------
__global__ __launch_bounds__(256) void gates_scores_kernel(const float* __restrict__ x,
                                                           const float* __restrict__ Wg, const float* __restrict__ bg,
                                                           const float* __restrict__ Ws, const float* __restrict__ bs,
                                                           float* __restrict__ gates, float* __restrict__ scores,
                                                           bf16* __restrict__ xb) {
    int row = blockIdx.x * 4 + (threadIdx.x >> 6);
    int lane = threadIdx.x & 63;
    const float* xr = x + (size_t)row * 1024 + lane * 16;
    float g0 = 0.f, g1 = 0.f, g2 = 0.f;
    double sc = 0.0;
    bf16x8 xo0, xo1;
#pragma unroll
    for (int i = 0; i < 16; i++) {
        float xv = xr[i];
        if (i < 8) xo0[i] = (bf16)xv; else xo1[i - 8] = (bf16)xv;
        int k = lane * 16 + i;
        g0 += xv * Wg[k * 3 + 0];
        g1 += xv * Wg[k * 3 + 1];
        g2 += xv * Wg[k * 3 + 2];
        sc += (double)(xv * Ws[k]);
    }
    bf16* xbp = xb + (size_t)row * 1024 + lane * 16;
    *(bf16x8*)xbp = xo0;
    *(bf16x8*)(xbp + 8) = xo1;
    for (int off = 1; off < 64; off <<= 1) {
        g0 += __shfl_xor(g0, off);
        g1 += __shfl_xor(g1, off);
        g2 += __shfl_xor(g2, off);
        sc += __shfl_xor(sc, off);
    }
    if (lane == 0) {
        g0 = 1.0f / (1.0f + __expf(-(g0 + bg[0])));
        g1 = 1.0f / (1.0f + __expf(-(g1 + bg[1])));
        g2 = 1.0f / (1.0f + __expf(-(g2 + bg[2])));
        float den = g0 + g1 + g2 + 1e-6f;
        gates[(size_t)row * 3 + 0] = g0 / den;
        gates[(size_t)row * 3 + 1] = g1 / den;
        gates[(size_t)row * 3 + 2] = g2 / den;
        scores[row] = (float)(sc + (double)bs[0]);
    }
}

// ---------------------------------------------------------------------------
// Top-k stage 1: PARTIAL rank counts. grid (16, 4, 4).
// ---------------------------------------------------------------------------
__global__ __launch_bounds__(256) void rank_kernel(const float* __restrict__ scores, int* __restrict__ rankP) {
    __shared__ float s[1024];
    const int b = blockIdx.z, jc = blockIdx.y;
    const int i = blockIdx.x * 256 + threadIdx.x;   // global query index
    const float* sb = scores + b * 4096;
    ((float4*)s)[threadIdx.x] = ((const float4*)(sb + jc * 1024))[threadIdx.x];
    __syncthreads();
    const float si = sb[i];
    const int jbase = jc * 1024;
    int cnt = 0;
#pragma unroll 4
    for (int jj = 0; jj < 1024; jj += 4) {
        float4 v = *(const float4*)(s + jj);
        int j0 = jbase + jj;
        cnt += (v.x > si) || (v.x == si && (j0 + 0) < i);
        cnt += (v.y > si) || (v.y == si && (j0 + 1) < i);
        cnt += (v.z > si) || (v.z == si && (j0 + 2) < i);
        cnt += (v.w > si) || (v.w == si && (j0 + 3) < i);
    }
    rankP[jc * 16384 + b * 4096 + i] = cnt;
}

// ---------------------------------------------------------------------------
// Top-k stage 2: sum partials; compact rank<512 in ascending-index order.
// ---------------------------------------------------------------------------
__global__ __launch_bounds__(1024) void select_kernel(const int* __restrict__ rankP, int* __restrict__ sidx) {
    __shared__ int psum[1024];
    int b = blockIdx.x, t = threadIdx.x;
    const int* rb = rankP + b * 4096;
    int f[4];
#pragma unroll
    for (int k = 0; k < 4; k++) {
        int idx = 4 * t + k;
        int r = rb[idx] + rb[16384 + idx] + rb[32768 + idx] + rb[49152 + idx];
        f[k] = r < 512;
    }
    psum[t] = f[0] + f[1] + f[2] + f[3];
    __syncthreads();
    for (int off = 1; off < 1024; off <<= 1) {
        int u = (t >= off) ? psum[t - off] : 0;
        __syncthreads();
        psum[t] += u;
        __syncthreads();
    }
    int pos = t ? psum[t - 1] : 0;
    int* ob = sidx + b * 512;
    if (f[0]) ob[pos++] = 4 * t + 0;
    if (f[1]) ob[pos++] = 4 * t + 1;
    if (f[2]) ob[pos++] = 4 * t + 2;
    if (f[3]) ob[pos++] = 4 * t + 3;
}

// ---------------------------------------------------------------------------
// add four fp32 partials + bias, convert to bf16 (comp K-split merge)
// ---------------------------------------------------------------------------
__global__ __launch_bounds__(256) void addcvt4_kernel(const float* __restrict__ P0, const float* __restrict__ P1,
                                                      const float* __restrict__ P2, const float* __restrict__ P3,
                                                      const float* __restrict__ bc, bf16* __restrict__ outp) {
    int i = blockIdx.x * 256 + threadIdx.x;    // 1,048,576 threads x 4 elems
    float4 a = ((const float4*)P0)[i];
    float4 b = ((const float4*)P1)[i];
    float4 c = ((const float4*)P2)[i];
    float4 d = ((const float4*)P3)[i];
    int col = (i << 2) & 1023;
    bf16x4 o;
    o[0] = (bf16)(a.x + b.x + c.x + d.x + bc[col + 0]);
    o[1] = (bf16)(a.y + b.y + c.y + d.y + bc[col + 1]);
    o[2] = (bf16)(a.z + b.z + c.z + d.z + bc[col + 2]);
    o[3] = (bf16)(a.w + b.w + c.w + d.w + bc[col + 3]);
    *(bf16x4*)(outp + ((size_t)i << 2)) = o;
}

// ---------------------------------------------------------------------------
// gemm3 body as device function (BT only): C(M,N) = A(M,K) @ Bt(N,K)^T + bias.
// m97 pattern: 128x128 tile, 16x16x32 bf16 MFMA, 4 waves, 4x4 frags.
// ---------------------------------------------------------------------------
template <bool F32OUT, bool ACC, bool REMAP>
__device__ __forceinline__ void gemm3_body(int nt, int mt, int zh, int zl, bf16* sA, bf16* sB,
                                           const bf16* __restrict__ A, const bf16* __restrict__ Bt,
                                           void* __restrict__ Cv, const float* __restrict__ bias, int biasz,
                                           int K, int lda, int ldb, int ldc,
                                           size_t sAhi, size_t sAlo, size_t sBhi, size_t sBlo,
                                           size_t sChi, size_t sClo, int mpbA, int mpbC) {
    const int t = threadIdx.x;
    const int lane = t & 63, quad = lane >> 4, l16 = lane & 15;
    const int wv = t >> 6, wm = wv >> 1, wn = wv & 1;
    A  += (size_t)zh * sAhi + (size_t)zl * sAlo;
    Bt += (size_t)zh * sBhi + (size_t)zl * sBlo;
    const size_t cofs = (size_t)zh * sChi + (size_t)zl * sClo;

    floatx4 acc[4][4] = {};

    const bf16* Ap = A + (size_t)(mt * 128 + (t >> 2)) * lda + (t & 3) * 8;
    const bf16* Bp = Bt + (size_t)(nt * 128 + (t >> 2)) * ldb + (t & 3) * 8;
    const size_t rA = (size_t)64 * lda, rB = (size_t)64 * ldb;
    bf16* lA0 = sA + wv * 512;          // wave-uniform LDS bases
    bf16* lA1 = sA + 2048 + wv * 512;
    bf16* lB0 = sB + wv * 512;
    bf16* lB1 = sB + 2048 + wv * 512;

    for (int k0 = 0; k0 < K; k0 += 32) {
        __syncthreads();
        GLDS(Ap + k0,      lA0);
        GLDS(Ap + rA + k0, lA1);
        GLDS(Bp + k0,      lB0);
        GLDS(Bp + rB + k0, lB1);
        __syncthreads();
        bf16x8 af[4], bfr[4];
#pragma unroll
        for (int i = 0; i < 4; i++) af[i] = *(const bf16x8*)(sA + (wm * 64 + i * 16 + l16) * 32 + quad * 8);
#pragma unroll
        for (int j = 0; j < 4; j++) bfr[j] = *(const bf16x8*)(sB + (wn * 64 + j * 16 + l16) * 32 + quad * 8);
#pragma unroll
        for (int i = 0; i < 4; i++)
#pragma unroll
            for (int j = 0; j < 4; j++) acc[i][j] = MFMA16(af[i], bfr[j], acc[i][j]);
    }

#pragma unroll
    for (int i = 0; i < 4; i++) {
        int gr0 = mt * 128 + wm * 64 + i * 16 + quad * 4;
#pragma unroll
        for (int j = 0; j < 4; j++) {
            int gc = nt * 128 + wn * 64 + j * 16 + l16;
            float bvl = bias ? bias[zl * biasz + gc] : 0.0f;
#pragma unroll
            for (int r = 0; r < 4; r++) {
                int row = gr0 + r;
                size_t crow = REMAP ? ((size_t)(row / mpbA) * mpbC + (row % mpbA)) : (size_t)row;
                size_t off = cofs + crow * ldc + gc;
                float v = acc[i][j][r] + bvl;
                if constexpr (F32OUT) {
                    float* Cf = (float*)Cv;
                    if constexpr (ACC) v += Cf[off];
                    Cf[off] = v;
                } else {
                    bf16* Cb = (bf16*)Cv;
                    if constexpr (ACC) v += (float)Cb[off];
                    Cb[off] = (bf16)v;
                }
            }
        }
    }
}

// ---------------------------------------------------------------------------
// original gemm3 kernel wrapper
// ---------------------------------------------------------------------------
template <bool NZF, bool F32OUT, bool ACC, bool REMAP>
__global__ __launch_bounds__(256) void gemm3(const bf16* __restrict__ A, const bf16* __restrict__ Bt,
                                             void* __restrict__ Cv, const float* __restrict__ bias, int biasz,
                                             int K, int lda, int ldb, int ldc, int zdiv,
                                             size_t sAhi, size_t sAlo, size_t sBhi, size_t sBlo,
                                             size_t sChi, size_t sClo, int mpbA, int mpbC) {
    __shared__ float4 smA[512], smB[512];  // 128x32 bf16 each
    const int mt = blockIdx.y;
    int nt, zh, zl;
    if constexpr (NZF) {
        zh = blockIdx.z;
        zl = blockIdx.x / zdiv;
        nt = blockIdx.x - zl * zdiv;
    } else {
        nt = blockIdx.x;
        int z = blockIdx.z;
        zh = z / zdiv;
        zl = z - zh * zdiv;
    }
    gemm3_body<F32OUT, ACC, REMAP>(nt, mt, zh, zl, (bf16*)smA, (bf16*)smB,
                                   A, Bt, Cv, bias, biasz, K, lda, ldb, ldc,
                                   sAhi, sAlo, sBhi, sBlo, sChi, sClo, mpbA, mpbC);
}

// ---------------------------------------------------------------------------
// gemm3_pair: TWO independent gemm3 problems in one dispatch.
// Grid: (max nx, max ny, nzA+nzB); side B bounds-checked.
// ---------------------------------------------------------------------------
template <bool F32OUT>
__global__ __launch_bounds__(256) void gemm3_pair(int nzA, int nxB, int nyB,
        const bf16* __restrict__ A1, const bf16* __restrict__ B1, void* __restrict__ C1,
        int K1, int lda1, int ldb1, int ldc1, size_t sAhi1, size_t sBhi1, size_t sChi1,
        const bf16* __restrict__ A2, const bf16* __restrict__ B2, void* __restrict__ C2,
        int K2, int lda2, int ldb2, int ldc2, size_t sAhi2, size_t sBhi2, size_t sChi2) {
    __shared__ float4 smA[512], smB[512];
    if ((int)blockIdx.z < nzA) {
        gemm3_body<F32OUT, false, false>(blockIdx.x, blockIdx.y, blockIdx.z, 0, (bf16*)smA, (bf16*)smB,
                                         A1, B1, C1, nullptr, 0, K1, lda1, ldb1, ldc1,
                                         sAhi1, 0, sBhi1, 0, sChi1, 0, 1, 1);
    } else {
        if ((int)blockIdx.x >= nxB || (int)blockIdx.y >= nyB) return;
        gemm3_body<F32OUT, false, false>(blockIdx.x, blockIdx.y, blockIdx.z - nzA, 0, (bf16*)smA, (bf16*)smB,
                                         A2, B2, C2, nullptr, 0, K2, lda2, ldb2, ldc2,
                                         sAhi2, 0, sBhi2, 0, sChi2, 0, 1, 1);
    }
}

// ---------------------------------------------------------------------------
// win QK^T (256 gemm3 blocks) + gather (1024 copy blocks) in one dispatch.
// ---------------------------------------------------------------------------
__global__ __launch_bounds__(256) void winqkt_gather_kernel(
        const bf16* __restrict__ qf, const bf16* __restrict__ kf, float* __restrict__ Swin,
        const bf16* __restrict__ Vf, const int* __restrict__ sidx,
        bf16* __restrict__ sq, bf16* __restrict__ sk, bf16* __restrict__ sv) {
    if ((int)blockIdx.x < 256) {
        __shared__ float4 smA[512], smB[512];
        int b = blockIdx.x;
        int nt = b & 1, mt = (b >> 1) & 1, zz = b >> 2;
        int zh = zz >> 4, zl = zz & 15;
        gemm3_body<true, false, false>(nt, mt, zh, zl, (bf16*)smA, (bf16*)smB,
                                       qf, kf, Swin, nullptr, 0, 1024, 1024, 1024, 256,
                                       (size_t)4194304, (size_t)131072, (size_t)4194304, (size_t)131072,
                                       (size_t)1048576, (size_t)65536, 1, 1);
        return;
    }
    int e = (blockIdx.x - 256) * 256 + threadIdx.x;
    int col = (e & 127) * 8;
    int i = (e >> 7) & 511;
    int b = e >> 16;
    int src = b * 4096 + (sidx[b * 512 + i] & 4095);
    size_t so = (size_t)src * 1024 + col;
    size_t dofs = (size_t)(b * 512 + i) * 1024 + col;
    *(float4*)(sq + dofs) = *(const float4*)(qf + so);
    *(float4*)(sk + dofs) = *(const float4*)(kf + so);
    *(float4*)(sv + dofs) = *(const float4*)(Vf + so);
}

// ---------------------------------------------------------------------------
// 256x256 8-phase GEMM (T2+T3+T4+T5). R16: phase layout ported faithfully to
// the m201 template: [reads; ST; BARRIER; lgkmcnt(0); MFMA; BARRIER] — reads
// issued BEFORE the barrier, full drain AFTER it. Wave-slippage overlap:
// after barrier release each wave starts MFMA as soon as its own counter
// clears, so fast waves' MFMAs overlap slow waves' LDS drain (m196: this
// interleave is the lever; m201 measured 62% MfmaUtil vs our 41%).
// __launch_bounds__(512,1): LDS (128KB) already limits to 1 block/CU; the
// old ",2" capped VGPR at 128 (R1's hidden spill cause).
// ST/vmcnt schedule unchanged from R3 (verified retire-set accounting):
// vmcnt(6) at p3/p7; WAR: each ST's region was last read >=2 phases earlier
// and drained at that phase's lgkmcnt(0) before its closing barrier.
// R4 lesson: conflict-free invariant requires 128B LDS rows.
// R8 LDS-staged vectorized epilogue. Grid product divisible by 8; K%128==0.
// ---------------------------------------------------------------------------
#define BARx()   asm volatile("s_barrier" ::: "memory")
#define LGKM0()  asm volatile("s_waitcnt lgkmcnt(0)" ::: "memory")
#define VMC6()   asm volatile("s_waitcnt vmcnt(6)" ::: "memory")

#define LD_A(bsel, qm) { \
    const bf16* _p = lds + (bsel) * 32768 + (((qm) << 7) + (wm << 6) + l16) * 64; \
    _Pragma("unroll") \
    for (int m = 0; m < 4; m++) { \
        a[m][0] = *(const bf16x8*)(_p + (m << 10) + cg0); \
        a[m][1] = *(const bf16x8*)(_p + (m << 10) + cg1); \
    } }

#define LD_B(bsel, qn) { \
    const bf16* _p = lds + (bsel) * 32768 + 16384 + (((qn) << 7) + (wn << 5) + l16) * 64; \
    _Pragma("unroll") \
    for (int n = 0; n < 2; n++) { \
        b[qn][n][0] = *(const bf16x8*)(_p + (n << 10) + cg0); \
        b[qn][n][1] = *(const bf16x8*)(_p + (n << 10) + cg1); \
    } }

#define ST_A(bsel, h, ko) { \
    bf16* _d = lds + (bsel) * 32768 + (((h) << 7) + (wv << 3)) * 64; \
    const bf16* _g = Ab + (size_t)((h) << 7) * lda + (ko); \
    GLDS(_g, _d); \
    GLDS(_g + ((size_t)lda << 6), _d + 4096); }

#define ST_B(bsel, h, ko) { \
    bf16* _d = lds + (bsel) * 32768 + 16384 + (((h) << 7) + (wv << 3)) * 64; \
    const bf16* _g = Bb + (size_t)((h) << 7) * ldb + (ko); \
    GLDS(_g, _d); \
    GLDS(_g + ((size_t)ldb << 6), _d + 4096); }

#define PH_MMA(qm, qn) { \
    __builtin_amdgcn_s_setprio(1); \
    _Pragma("unroll") \
    for (int kk = 0; kk < 2; kk++) \
    _Pragma("unroll") \
    for (int m = 0; m < 4; m++) \
    _Pragma("unroll") \
    for (int n = 0; n < 2; n++) \
        acc[qm][qn][m][n] = MFMA16(a[m][kk], b[qn][n][kk], acc[qm][qn][m][n]); \
    __builtin_amdgcn_s_setprio(0); }

template <bool F32OUT, bool ACC, bool REMAP>
__device__ __forceinline__ void gemm256_body(int mt, int nt, int zh, int zl, float4* ldsv,
        const bf16* __restrict__ A, const bf16* __restrict__ Bt,
        void* __restrict__ Cv, const float* __restrict__ bias, int biasz,
        int K, int lda, int ldb, int ldc,
        size_t sAhi, size_t sAlo, size_t sBhi, size_t sBlo,
        size_t sChi, size_t sClo, int mpbA, int mpbC) {
    bf16* lds = (bf16*)ldsv;
    const int t = threadIdx.x;
    const int lane = t & 63, quad = lane >> 4, l16 = lane & 15;
    const int wv = t >> 6, wm = wv >> 2, wn = wv & 3;

    A  += (size_t)zh * sAhi + (size_t)zl * sAlo;
    Bt += (size_t)zh * sBhi + (size_t)zl * sBlo;
    const size_t cofs = (size_t)zh * sChi + (size_t)zl * sClo;

    // staging: wave wv stages rows wv*8+(lane>>3) of each 64-row call block;
    // global source column pre-swizzled so LDS stays linear (m104 constraint)
    const int srow = (wv << 3) + (lane >> 3);
    const int scol = (((lane & 7) ^ ((lane >> 3) & 7)) << 3);
    const bf16* Ab = A + (size_t)(mt * 256 + srow) * lda + scol;
    const bf16* Bb = Bt + (size_t)(nt * 256 + srow) * ldb + scol;
    const int swz = l16 & 7;
    const int cg0 = ((quad ^ swz) << 3);         // kk=0 16B-granule (elements)
    const int cg1 = (((4 | quad) ^ swz) << 3);   // kk=1

    floatx4 acc[2][2][4][2] = {};
    bf16x8 a[4][2], b[2][2][2];     // A single-buffered, B kept per-qn

    const int NT = K >> 6;          // 64-wide K-tiles; K % 128 == 0 required
    // prologue: both tiles fully staged
    ST_A(0, 0, 0);  ST_B(0, 0, 0);  ST_B(0, 1, 0);  ST_A(0, 1, 0);
    ST_A(1, 0, 64); ST_B(1, 0, 64); ST_B(1, 1, 64); ST_A(1, 1, 64);
    VMC6();                          // 16 issued -> tile0's 8 + b1.Ah0 landed
    BARx();

#pragma unroll 1
    for (int it = 0; it < (NT >> 1); ++it) {
        const int kt = it << 1;
        const int ko2 = ((kt + 2 < NT) ? kt + 2 : NT - 1) << 6;     // clamped: staged-but-unread past end
        const int ko3 = ((kt + 3 < NT) ? kt + 3 : NT - 1) << 6;
        // p0: q(0,0) buf0 — no ST
        LD_B(0, 0); LD_A(0, 0);
        BARx(); LGKM0();
        PH_MMA(0, 0);
        BARx();
        // p1: q(0,1)
        LD_B(0, 1);
        ST_A(0, 0, ko2);
        BARx(); LGKM0();
        PH_MMA(0, 1);
        BARx();
        // p2: q(1,1)
        LD_A(0, 1);
        ST_B(0, 0, ko2);
        BARx(); LGKM0();
        PH_MMA(1, 1);
        BARx();
        // p3: q(1,0) — no reads; vmcnt checkpoint
        ST_B(0, 1, ko2);
        BARx();
        PH_MMA(1, 0);
        VMC6();
        BARx();
        // p4: q(0,0) buf1
        LD_B(1, 0); LD_A(1, 0);
        ST_A(0, 1, ko2);
        BARx(); LGKM0();
        PH_MMA(0, 0);
        BARx();
        // p5: q(0,1)
        LD_B(1, 1);
        ST_A(1, 0, ko3);
        BARx(); LGKM0();
        PH_MMA(0, 1);
        BARx();
        // p6: q(1,1)
        LD_A(1, 1);
        ST_B(1, 0, ko3);
        BARx(); LGKM0();
        PH_MMA(1, 1);
        BARx();
        // p7: q(1,0) — two STs; vmcnt checkpoint
        ST_B(1, 1, ko3);
        ST_A(1, 1, ko3);
        BARx();
        PH_MMA(1, 0);
        VMC6();
        BARx();
    }

    // ---- epilogue ----
    asm volatile("s_waitcnt vmcnt(0)" ::: "memory");
    BARx();

    if constexpr (!ACC && !REMAP) {
        const int STE = F32OUT ? 260 : 264;
        float* ldsf = (float*)ldsv;
        bf16* ldsh = (bf16*)ldsv;
#pragma unroll
        for (int qm = 0; qm < 2; qm++)
#pragma unroll
        for (int mh = 0; mh < 2; mh++) {
#pragma unroll
            for (int qn = 0; qn < 2; qn++)
#pragma unroll
            for (int n = 0; n < 2; n++) {
                const int ccol = qn * 128 + wn * 32 + n * 16 + l16;
                const float bvl = bias ? bias[zl * biasz + nt * 256 + ccol] : 0.0f;
#pragma unroll
                for (int mp = 0; mp < 2; mp++) {
                    const int lr0 = wm * 32 + mp * 16 + quad * 4;
#pragma unroll
                    for (int r = 0; r < 4; r++) {
                        float v = acc[qm][qn][mh * 2 + mp][n][r] + bvl;
                        if constexpr (F32OUT) ldsf[(lr0 + r) * STE + ccol] = v;
                        else                  ldsh[(lr0 + r) * STE + ccol] = (bf16)v;
                    }
                }
            }
            LGKM0(); BARx();
            if constexpr (F32OUT) {
                float* Cf = (float*)Cv;
#pragma unroll
                for (int i = 0; i < 8; i++) {
                    int idx = i * 512 + t;
                    int row = idx >> 6, c4 = (idx & 63) << 2;
                    float4 vv = *(float4*)(ldsf + row * STE + c4);
                    int grow = mt * 256 + qm * 128 + ((row >> 5) << 6) + mh * 32 + (row & 31);
                    *(float4*)(Cf + cofs + (size_t)grow * ldc + nt * 256 + c4) = vv;
                }
            } else {
                bf16* Cb = (bf16*)Cv;
#pragma unroll
                for (int i = 0; i < 4; i++) {
                    int idx = i * 512 + t;
                    int row = idx >> 5, c8 = (idx & 31) << 3;
                    float4 vv = *(float4*)(ldsh + row * STE + c8);
                    int grow = mt * 256 + qm * 128 + ((row >> 5) << 6) + mh * 32 + (row & 31);
                    *(float4*)(Cb + cofs + (size_t)grow * ldc + nt * 256 + c8) = vv;
                }
            }
            LGKM0(); BARx();
        }
    } else {
        // scalar fallback (unused by current call sites)
#pragma unroll
        for (int qm = 0; qm < 2; qm++)
#pragma unroll
        for (int m = 0; m < 4; m++) {
            int gr0 = mt * 256 + qm * 128 + wm * 64 + m * 16 + quad * 4;
#pragma unroll
            for (int qn = 0; qn < 2; qn++)
#pragma unroll
            for (int n = 0; n < 2; n++) {
                int gc = nt * 256 + qn * 128 + wn * 32 + n * 16 + l16;
                float bvl = bias ? bias[zl * biasz + gc] : 0.0f;
#pragma unroll
                for (int r = 0; r < 4; r++) {
                    int row = gr0 + r;
                    size_t crow = REMAP ? ((size_t)(row / mpbA) * mpbC + (row % mpbA)) : (size_t)row;
                    size_t off = cofs + crow * ldc + gc;
                    float v = acc[qm][qn][m][n][r] + bvl;
                    if constexpr (F32OUT) {
                        float* Cf = (float*)Cv;
                        if constexpr (ACC) v += Cf[off];
                        Cf[off] = v;
                    } else {
                        bf16* Cb = (bf16*)Cv;
                        if constexpr (ACC) v += (float)Cb[off];
                        Cb[off] = (bf16)v;
                    }
                }
            }
        }
    }
}

template <bool NZF, bool F32OUT, bool ACC, bool REMAP>
__global__ __launch_bounds__(512, 1) void gemm256(const bf16* __restrict__ A, const bf16* __restrict__ Bt,
                                                  void* __restrict__ Cv, const float* __restrict__ bias, int biasz,
                                                  int K, int lda, int ldb, int ldc, int zdiv,
                                                  size_t sAhi, size_t sAlo, size_t sBhi, size_t sBlo,
                                                  size_t sChi, size_t sClo, int mpbA, int mpbC) {
    __shared__ float4 ldsv[8192];   // 128 KiB: buf0 {A|B} , buf1 {A|B}
    // XCD-chunked bijective remap over (x,y); callers guarantee nwg % 8 == 0
    const int gx = gridDim.x;
    int lin = blockIdx.x + gx * blockIdx.y;
    const int chunk = (gx * gridDim.y) >> 3;
    lin = (lin & 7) * chunk + (lin >> 3);
    const int bx = lin % gx;
    const int mt = lin / gx;

    int nt, zh, zl;
    if constexpr (NZF) {
        zh = blockIdx.z;
        zl = bx / zdiv;
        nt = bx - zl * zdiv;
    } else {
        nt = bx;
        int z = blockIdx.z;
        zh = z / zdiv;
        zl = z - zh * zdiv;
    }
    gemm256_body<F32OUT, ACC, REMAP>(mt, nt, zh, zl, ldsv, A, Bt, Cv, bias, biasz,
                                     K, lda, ldb, ldc, sAhi, sAlo, sBhi, sBlo, sChi, sClo, mpbA, mpbC);
}

#undef LD_A
#undef LD_B
#undef ST_A
#undef ST_B
#undef PH_MMA

// ---------------------------------------------------------------------------
// shared softmax / transpose device helpers
// ---------------------------------------------------------------------------
__device__ __forceinline__ void sm_body(const float* __restrict__ srow, bf16* __restrict__ prow,
                                        int npt, float gate, float* red) {
    const int t = threadIdx.x;
    float v[4];
    float m = -1e30f;
    for (int i = 0; i < npt; i++) { v[i] = srow[t + (i << 8)] * SCALE_F; m = fmaxf(m, v[i]); }
    for (int off = 1; off < 64; off <<= 1) m = fmaxf(m, __shfl_xor(m, off));
    const int wvv = t >> 6, lane = t & 63;
    if (lane == 0) red[wvv] = m;
    __syncthreads();
    m = fmaxf(fmaxf(red[0], red[1]), fmaxf(red[2], red[3]));
    float e[4], s = 0.f;
    for (int i = 0; i < npt; i++) { e[i] = __expf(v[i] - m); s += e[i]; }
    for (int off = 1; off < 64; off <<= 1) s += __shfl_xor(s, off);
    if (lane == 0) red[4 + wvv] = s;
    __syncthreads();
    s = red[4] + red[5] + red[6] + red[7];
    const float fac = gate / s;
    for (int i = 0; i < npt; i++) prow[t + (i << 8)] = (bf16)(e[i] * fac);
}

__device__ __forceinline__ void tp_body(const bf16* __restrict__ tin, bf16* __restrict__ tout,
                                        int TR, int TC, int tb, bf16 (*tile)[33]) {
    const int t = threadIdx.x;
    int bx = (tb & 31) * 32, by = (tb >> 5) * 32;
    int tx = t & 31, ty = t >> 5;
#pragma unroll
    for (int i = 0; i < 32; i += 8)
        tile[ty + i][tx] = tin[(size_t)(by + ty + i) * TC + bx + tx];
    __syncthreads();
#pragma unroll
    for (int i = 0; i < 32; i += 8)
        tout[(size_t)(bx + ty + i) * TR + by + tx] = tile[tx][ty + i];
}

// ---------------------------------------------------------------------------
// Merged win softmax + vf transpose
// ---------------------------------------------------------------------------
__global__ __launch_bounds__(256) void smtb_win_kernel(const float* __restrict__ S, bf16* __restrict__ P,
                                                       const float* __restrict__ gates, int nsm,
                                                       const bf16* __restrict__ tin, bf16* __restrict__ tout) {
    __shared__ float red[8];
    __shared__ bf16 tile[32][33];
    if ((int)blockIdx.x >= nsm) {
        tp_body(tin, tout, 16384, 1024, blockIdx.x - nsm, tile);
        return;
    }
    const int row = blockIdx.x;
    int zz = row >> 8;
    int gpos = (zz / 16) * 4096 + (zz % 16) * 256 + (row & 255);
    sm_body(S + (size_t)row * 256, P + (size_t)row * 256, 1, gates[gpos * 3 + 2], red);
}

// ---------------------------------------------------------------------------
// Merged comp+sel softmax + cv/sv transposes (4 independent block ranges)
// ---------------------------------------------------------------------------
__global__ __launch_bounds__(256) void smtb2_kernel(const float* __restrict__ S0, bf16* __restrict__ P0,
                                                    const float* __restrict__ S1, bf16* __restrict__ P1,
                                                    const float* __restrict__ gates,
                                                    const bf16* __restrict__ cv, bf16* __restrict__ cvT,
                                                    const bf16* __restrict__ sv, bf16* __restrict__ svT) {
    __shared__ float red[8];
    __shared__ bf16 tile[32][33];
    const int i = blockIdx.x;
    if (i < 4096) {
        int gpos = (i >> 10) * 4096 + (i & 1023);
        sm_body(S0 + (size_t)i * 1024, P0 + (size_t)i * 1024, 4, gates[gpos * 3 + 0], red);
    } else if (i < 8192) {
        tp_body(cv, cvT, 4096, 1024, i - 4096, tile);
    } else if (i < 10240) {
        int row = i - 8192;
        int gpos = (row >> 9) * 4096 + (row & 511);
        sm_body(S1 + (size_t)row * 512, P1 + (size_t)row * 512, 2, gates[gpos * 3 + 1], red);
    } else {
        tp_body(sv, svT, 2048, 1024, i - 10240, tile);
    }
}

// ---------------------------------------------------------------------------
// Residual (0.5/0.5) + partial sums + LayerNorm, in-place on fp32 out.
// out_row += compPr (idx<1024) += selPr (idx<512): same fp32 add order as
// the old serial ACC chain -> bitwise identical.
// ---------------------------------------------------------------------------
__global__ __launch_bounds__(256) void ln_kernel(float* __restrict__ acc, const float* __restrict__ x,
                                                 const float* __restrict__ compPr, const float* __restrict__ selPr) {
    __shared__ float red[8];
    int row = blockIdx.x, t = threadIdx.x;
    int b = row >> 12, idx = row & 4095;
    float4 a = ((const float4*)(acc + (size_t)row * 1024))[t];
    if (idx < 1024) {
        float4 c = ((const float4*)(compPr + (size_t)(b * 1024 + idx) * 1024))[t];
        a.x += c.x; a.y += c.y; a.z += c.z; a.w += c.w;
    }
    if (idx < 512) {
        float4 s4 = ((const float4*)(selPr + (size_t)(b * 512 + idx) * 1024))[t];
        a.x += s4.x; a.y += s4.y; a.z += s4.z; a.w += s4.w;
    }
    float4 xv = ((const float4*)(x + (size_t)row * 1024))[t];
    float y[4];
    y[0] = 0.5f * a.x + 0.5f * xv.x;
    y[1] = 0.5f * a.y + 0.5f * xv.y;
    y[2] = 0.5f * a.z + 0.5f * xv.z;
    y[3] = 0.5f * a.w + 0.5f * xv.w;
    float s = 0.f, s2 = 0.f;
#pragma unroll
    for (int i = 0; i < 4; i++) { s += y[i]; s2 += y[i] * y[i]; }
    for (int off = 1; off < 64; off <<= 1) { s += __shfl_xor(s, off); s2 += __shfl_xor(s2, off); }
    int wvv = t >> 6, lane = t & 63;
    if (lane == 0) { red[wvv] = s; red[4 + wvv] = s2; }
    __syncthreads();
    s = red[0] + red[1] + red[2] + red[3];
    s2 = red[4] + red[5] + red[6] + red[7];
    float mu = s * (1.0f / 1024.0f);
    float var = s2 * (1.0f / 1024.0f) - mu * mu;
    float rs = rsqrtf(var + 1e-6f);
    float4 o;
    o.x = (y[0] - mu) * rs;
    o.y = (y[1] - mu) * rs;
    o.z = (y[2] - mu) * rs;
    o.w = (y[3] - mu) * rs;
    ((float4*)(acc + (size_t)row * 1024))[t] = o;
}

// ---------------------------------------------------------------------------
extern "C" void kernel_launch(void* const* d_in, const int* in_sizes, int n_in,
                              void* d_out, int out_size, void* d_ws, size_t ws_size,
                              hipStream_t stream) {
    (void)in_sizes; (void)n_in; (void)out_size; (void)ws_size;
    const float* x  = (const float*)d_in[0];
    const float* Wq = (const float*)d_in[1];
    const float* bq = (const float*)d_in[2];
    const float* Wk = (const float*)d_in[3];
    const float* bk = (const float*)d_in[4];
    const float* Wv = (const float*)d_in[5];
    const float* bv = (const float*)d_in[6];
    const float* Wo = (const float*)d_in[7];
    const float* bo = (const float*)d_in[8];
    const float* Wg = (const float*)d_in[9];
    const float* bg = (const float*)d_in[10];
    const float* Wc = (const float*)d_in[11];
    const float* bc = (const float*)d_in[12];
    const float* Ws = (const float*)d_in[13];
    const float* bs = (const float*)d_in[14];
    float* out = (float*)d_out;

    // ---- workspace (~189 MB peak; phase-ordered region reuse) ----
    char* w = (char*)d_ws;
    const size_t MB = 1024 * 1024;
    // region A (0..32): xb [gates->compGEMM] -> Pwin [win] -> cq/ck/cv/Pcomp [comp branch]
    bf16* xb    = (bf16*)(w + 0 * MB);    // 32
    bf16* Pwin  = (bf16*)(w + 0 * MB);    // 8
    bf16* cq    = (bf16*)(w + 0 * MB);    // 8
    bf16* ck    = (bf16*)(w + 8 * MB);    // 8
    bf16* cv    = (bf16*)(w + 16 * MB);   // 8
    bf16* Pcomp = (bf16*)(w + 24 * MB);   // 8
    // sel small buffers (live after merged QK^T; cq/ck dead then)
    bf16* Psel  = (bf16*)(w + 4 * MB);    // 2
    bf16* sel_o = (bf16*)(w + 6 * MB);    // 4
    // mid regions
    bf16* qf    = (bf16*)(w + 32 * MB);   // 32 [QKV -> S_win]
    bf16* vfT   = (bf16*)(w + 32 * MB);   // 32 [after S_win]
    bf16* kf    = (bf16*)(w + 64 * MB);   // 32 [QKV -> S_win]
    bf16* win_o = (bf16*)(w + 64 * MB);   // 32 [after S_win]
    bf16* vf    = (bf16*)(w + 96 * MB);   // 32 [QKV -> vfT transpose/gather]
    bf16* comp  = (bf16*)(w + 128 * MB);  // 8  [compGEMM -> comp qkv]
    // comp K-split partials (4 x 16 MB fp32) overlay qf/kf (dead until QKV)
    float* compP = (float*)(w + 32 * MB); // 64 [32..96]
    // projection partials overlay vfT region (dead after win-PV):
    float* compPr = (float*)(w + 32 * MB); // 16 [32..48]
    float* selPr  = (float*)(w + 48 * MB); // 8  [48..56]
    // rank partials (256 KB) overlay vf (dead until QKV gemm writes it)
    int* rankP = (int*)(w + 96 * MB);
    // cvT in vf region (96..104): vf dead after win-branch transpose
    bf16* cvT = (bf16*)(w + 96 * MB);     // 8 [comp branch only]
    // Ssel at 104..108 (vf region, dead at comp-branch time)
    float* SselN = (float*)(w + 104 * MB); // 4
    // region B (136..152): Swin [win] -> Scomp [comp] -> comp_o
    float* Swin  = (float*)(w + 136 * MB);  // 16
    float* Scomp = (float*)(w + 136 * MB);  // 16
    bf16* comp_o = (bf16*)(w + 144 * MB);   // 8
    // weights (transposed bf16)
    bf16* wqkvT = (bf16*)(w + 152 * MB);  // 6 (wq|wk|wv, 1024-row segments)
    bf16* wcT   = (bf16*)(w + 158 * MB);  // 8
    bf16* woT0  = (bf16*)(w + 166 * MB);  // 2
    bf16* woT1  = (bf16*)(w + 168 * MB);  // 2
    bf16* woT2  = (bf16*)(w + 170 * MB);  // 2
    // sel gather buffers (parked high; live gather -> sel branch)
    bf16* sq    = (bf16*)(w + 172 * MB);  // 4
    bf16* sk    = (bf16*)(w + 176 * MB);  // 4
    bf16* sv    = (bf16*)(w + 180 * MB);  // 4
    bf16* svT   = (bf16*)(w + 184 * MB);  // 4
    // smalls
    float* bqkv    = (float*)(w + 188 * MB);
    float* gatesF  = bqkv + 3072;
    float* scoresF = gatesF + 49152;
    int*   sidx    = (int*)(scoresF + 16384);

    dim3 tb(32, 8);

    // ---- prep: gates+scores+x->bf16 (fused); all transposes + bconcat; topk ----
    gates_scores_kernel<<<4096, 256, 0, stream>>>(x, Wg, bg, Ws, bs, gatesF, scoresF, xb);
    prep_kernel<<<dim3(32, 32, 11), tb, 0, stream>>>(Wq, Wk, Wv, Wo, Wc, bq, bk, bv, wqkvT, woT0, wcT, bqkv);
    rank_kernel<<<dim3(16, 4, 4), 256, 0, stream>>>(scoresF, rankP);
    select_kernel<<<4, 1024, 0, stream>>>(rankP, sidx);

    // ---- compressed tokens FIRST (qf/kf free): 4-way K-split + merge ----
    gemm256<false,true,false,false><<<dim3(4, 16, 4), 512, 0, stream>>>(
        xb, wcT, compP, nullptr, 0, 1024, 4096, 4096, 1024, 1,
        (size_t)1024, 0, (size_t)1024, 0, (size_t)4194304, 0, 1, 1);
    addcvt4_kernel<<<4096, 256, 0, stream>>>(compP, compP + (size_t)4194304,
                                             compP + (size_t)8388608, compP + (size_t)12582912, bc, comp);

    // ---- fused Q/K/V: 256^2 8-phase, N-fused z ----
    gemm256<true,false,false,false><<<dim3(12, 64, 1), 512, 0, stream>>>(
        xb, wqkvT, qf, bqkv, 1024, 1024, 1024, 1024, 1024, 4,
        0, 0, 0, (size_t)1048576, 0, (size_t)16777216, 1, 1);

    // ---- merged: win QK^T (256 gemm3 blocks) + gather (1024 copy blocks) ----
    winqkt_gather_kernel<<<1280, 256, 0, stream>>>(qf, kf, Swin, vf, sidx, sq, sk, sv);

    // ---- win softmax + vf transpose ----
    smtb_win_kernel<<<32768, 256, 0, stream>>>(Swin, Pwin, gatesF, 16384, vf, vfT);
    gemm3<false,false,false,false><<<dim3(8, 2, 64), 256, 0, stream>>>(
        Pwin, vfT, win_o, nullptr, 0, 256, 256, 16384, 1024, 16,
        (size_t)1048576, (size_t)65536, (size_t)4096, (size_t)128, (size_t)4194304, (size_t)262144, 1, 1);
    // ---- win projection (gemm256, 256 blocks = 1 full round) -> out + bo ----
    gemm256<false,true,false,false><<<dim3(4, 64, 1), 512, 0, stream>>>(
        win_o, woT2, out, bo, 0, 1024, 1024, 1024, 1024, 1, 0, 0, 0, 0, 0, 0, 1, 1);

    // ---- COMP QKV (needed by merged QK^T pair) ----
    gemm256<true,false,false,false><<<dim3(12, 16, 1), 512, 0, stream>>>(
        comp, wqkvT, cq, bqkv, 1024, 1024, 1024, 1024, 1024, 4,
        0, 0, 0, (size_t)1048576, 0, (size_t)4194304, 1, 1);

    // ---- merged QK^T: Scomp (cq@ck) + Ssel (sq@sk) in one dispatch ----
    gemm3_pair<true><<<dim3(8, 8, 8), 256, 0, stream>>>(4, 4, 4,
        cq, ck, Scomp, 1024, 1024, 1024, 1024, (size_t)1048576, (size_t)1048576, (size_t)1048576,
        sq, sk, SselN, 1024, 1024, 1024, 512, (size_t)524288, (size_t)524288, (size_t)262144);

    // ---- merged softmaxes + V transposes (comp + sel) ----
    smtb2_kernel<<<12288, 256, 0, stream>>>(Scomp, Pcomp, SselN, Psel, gatesF, cv, cvT, sv, svT);

    // ---- merged PV: comp (Pcomp@cvT) + sel (Psel@svT) ----
    gemm3_pair<false><<<dim3(8, 8, 8), 256, 0, stream>>>(4, 8, 4,
        Pcomp, cvT, comp_o, 1024, 1024, 4096, 1024, (size_t)1048576, (size_t)1024, (size_t)1048576,
        Psel, svT, sel_o, 512, 512, 2048, 1024, (size_t)262144, (size_t)512, (size_t)524288);

    // ---- comp/sel projections -> fp32 partials (summed in ln, same fp32
    //      add order as the old ACC chain) ----
    gemm3_pair<true><<<dim3(8, 32, 2), 256, 0, stream>>>(1, 8, 16,
        comp_o, woT0, compPr, 1024, 1024, 1024, 1024, 0, 0, 0,
        sel_o, woT1, selPr, 1024, 1024, 1024, 1024, 0, 0, 0);

    // ---- residual + partial sums + LN in place on fp32 d_out ----
    ln_kernel<<<16384, 256, 0, stream>>>(out, x, compPr, selPr);
}